// Round 1
// baseline (57.391 us; speedup 1.0000x reference)
//
#include <hip/hip_runtime.h>

#define DELTA 0.05f
#define EPS 1e-8f

// ---------------------------------------------------------------------------
// Precompute per-gaussian packed record: [S00,S01,S02,S11][S12,S22,mux,muy][muz,color,0,0]
// Sigma = R diag(s^2) R^T  (scale_scale = 1)
// ---------------------------------------------------------------------------
__global__ __launch_bounds__(256) void precompute_gauss(
    const float* __restrict__ mu,
    const float* __restrict__ scaling,
    const float* __restrict__ rot,
    const float* __restrict__ color,
    float4* __restrict__ table, int G)
{
    int g = blockIdx.x * blockDim.x + threadIdx.x;
    if (g >= G) return;
    float qw = rot[g*4+0], qx = rot[g*4+1], qy = rot[g*4+2], qz = rot[g*4+3];
    float inv_norm = rsqrtf(qw*qw + qx*qx + qy*qy + qz*qz + EPS);
    qw *= inv_norm; qx *= inv_norm; qy *= inv_norm; qz *= inv_norm;
    float x2 = qx*qx, y2 = qy*qy, z2 = qz*qz;
    float xy = qx*qy, xz = qx*qz, yz = qy*qz;
    float wx = qw*qx, wy = qw*qy, wz = qw*qz;
    float R00 = 1.f - 2.f*(y2 + z2), R01 = 2.f*(xy - wz),       R02 = 2.f*(xz + wy);
    float R10 = 2.f*(xy + wz),       R11 = 1.f - 2.f*(x2 + z2), R12 = 2.f*(yz - wx);
    float R20 = 2.f*(xz - wy),       R21 = 2.f*(yz + wx),       R22 = 1.f - 2.f*(x2 + y2);
    float s0 = scaling[g*3+0], s1 = scaling[g*3+1], s2 = scaling[g*3+2];
    float d0 = s0*s0, d1 = s1*s1, d2 = s2*s2;
    // Sigma[i][j] = sum_k R[i][k]*d[k]*R[j][k]
    float S00 = R00*R00*d0 + R01*R01*d1 + R02*R02*d2;
    float S01 = R00*R10*d0 + R01*R11*d1 + R02*R12*d2;
    float S02 = R00*R20*d0 + R01*R21*d1 + R02*R22*d2;
    float S11 = R10*R10*d0 + R11*R11*d1 + R12*R12*d2;
    float S12 = R10*R20*d0 + R11*R21*d1 + R12*R22*d2;
    float S22 = R20*R20*d0 + R21*R21*d1 + R22*R22*d2;
    float mx = mu[g*3+0], my = mu[g*3+1], mz = mu[g*3+2];
    float col = color[g];
    table[g*3+0] = make_float4(S00, S01, S02, S11);
    table[g*3+1] = make_float4(S12, S22, mx, my);
    table[g*3+2] = make_float4(mz, col, 0.f, 0.f);
}

// ---------------------------------------------------------------------------
// Main kernel: one lane per (point, k). 32 lanes per point, 2 points per wave.
// ---------------------------------------------------------------------------
template <bool USE_TABLE>
__global__ __launch_bounds__(256) void gsvr_main(
    const float* __restrict__ coords,
    const float* __restrict__ psf,
    const int*   __restrict__ idcs,
    const float4* __restrict__ table,
    const float* __restrict__ mu,
    const float* __restrict__ scaling,
    const float* __restrict__ rot,
    const float* __restrict__ color,
    float* __restrict__ out, int n_pts)
{
    int tid = blockIdx.x * blockDim.x + threadIdx.x;
    int p  = tid >> 5;
    int kk = tid & 31;
    if (p >= n_pts) return;

    float cx = coords[p*3+0], cy = coords[p*3+1], cz = coords[p*3+2];
    const float* sp = psf + (size_t)p*9;
    float pa = sp[0], pb = sp[1], pc = sp[2], pe = sp[4], pf = sp[5], pi = sp[8];

    int g = idcs[p*32 + kk];

    float S00, S01, S02, S11, S12, S22, mx, my, mz, col;
    if (USE_TABLE) {
        float4 t0 = table[(size_t)g*3+0];
        float4 t1 = table[(size_t)g*3+1];
        float4 t2 = table[(size_t)g*3+2];
        S00 = t0.x; S01 = t0.y; S02 = t0.z; S11 = t0.w;
        S12 = t1.x; S22 = t1.y; mx = t1.z; my = t1.w;
        mz = t2.x; col = t2.y;
    } else {
        float qw = rot[g*4+0], qx = rot[g*4+1], qy = rot[g*4+2], qz = rot[g*4+3];
        float inv_norm = rsqrtf(qw*qw + qx*qx + qy*qy + qz*qz + EPS);
        qw *= inv_norm; qx *= inv_norm; qy *= inv_norm; qz *= inv_norm;
        float x2 = qx*qx, y2 = qy*qy, z2 = qz*qz;
        float xy = qx*qy, xz = qx*qz, yz = qy*qz;
        float wx = qw*qx, wy = qw*qy, wz = qw*qz;
        float R00 = 1.f - 2.f*(y2 + z2), R01 = 2.f*(xy - wz),       R02 = 2.f*(xz + wy);
        float R10 = 2.f*(xy + wz),       R11 = 1.f - 2.f*(x2 + z2), R12 = 2.f*(yz - wx);
        float R20 = 2.f*(xz - wy),       R21 = 2.f*(yz + wx),       R22 = 1.f - 2.f*(x2 + y2);
        float s0 = scaling[g*3+0], s1 = scaling[g*3+1], s2 = scaling[g*3+2];
        float d0 = s0*s0, d1 = s1*s1, d2 = s2*s2;
        S00 = R00*R00*d0 + R01*R01*d1 + R02*R02*d2;
        S01 = R00*R10*d0 + R01*R11*d1 + R02*R12*d2;
        S02 = R00*R20*d0 + R01*R21*d1 + R02*R22*d2;
        S11 = R10*R10*d0 + R11*R11*d1 + R12*R12*d2;
        S12 = R10*R20*d0 + R11*R21*d1 + R12*R22*d2;
        S22 = R20*R20*d0 + R21*R21*d1 + R22*R22*d2;
        mx = mu[g*3+0]; my = mu[g*3+1]; mz = mu[g*3+2];
        col = color[g];
    }

    // sig = Sigma_g + Sigma_psf
    float a = S00 + pa, b = S01 + pb, c = S02 + pc;
    float e = S11 + pe, f = S12 + pf, i = S22 + pi;
    float vx = cx - mx, vy = cy - my, vz = cz - mz;

    // explicit symmetric 3x3 inverse (same formula as reference)
    float ei_fh = e*i - f*f;
    float det = a*ei_fh - b*(b*i - f*c) + c*(b*f - e*c);
    float inv_det = 1.0f / (det + EPS);
    float i00 = ei_fh * inv_det;
    float i01 = (c*f - b*i) * inv_det;
    float i02 = (b*f - c*e) * inv_det;
    float i11 = (a*i - c*c) * inv_det;
    float i12 = (c*b - a*f) * inv_det;
    float i22 = (a*e - b*b) * inv_det;

    float q0 = i00*vx + i01*vy + i02*vz;
    float q1 = i01*vx + i11*vy + i12*vz;
    float q2 = i02*vx + i12*vy + i22*vz;
    float inner = vx*q0 + vy*q1 + vz*q2;

    float w  = __expf(-0.5f * inner);
    float wc = w * col;

    // butterfly reduce across the 32-lane group (masks <=16 stay in-half)
    #pragma unroll
    for (int m = 16; m >= 1; m >>= 1) {
        w  += __shfl_xor(w,  m);
        wc += __shfl_xor(wc, m);
    }
    if (kk == 0) out[p] = wc / (w + DELTA);
}

extern "C" void kernel_launch(void* const* d_in, const int* in_sizes, int n_in,
                              void* d_out, int out_size, void* d_ws, size_t ws_size,
                              hipStream_t stream)
{
    const float* coords  = (const float*)d_in[0];
    const float* psf     = (const float*)d_in[1];
    const float* mu      = (const float*)d_in[2];
    const float* scaling = (const float*)d_in[3];
    const float* rot     = (const float*)d_in[4];
    const float* color   = (const float*)d_in[5];
    const int*   idcs    = (const int*)d_in[6];
    float* out = (float*)d_out;

    int n_pts = in_sizes[0] / 3;
    int G     = in_sizes[5];

    size_t need = (size_t)G * 12 * sizeof(float);
    int main_blocks = (n_pts * 32 + 255) / 256;

    if (ws_size >= need) {
        float4* table = (float4*)d_ws;
        precompute_gauss<<<(G + 255) / 256, 256, 0, stream>>>(mu, scaling, rot, color, table, G);
        gsvr_main<true><<<main_blocks, 256, 0, stream>>>(
            coords, psf, idcs, table, nullptr, nullptr, nullptr, nullptr, out, n_pts);
    } else {
        gsvr_main<false><<<main_blocks, 256, 0, stream>>>(
            coords, psf, idcs, nullptr, mu, scaling, rot, color, out, n_pts);
    }
}